// Round 11
// baseline (222.751 us; speedup 1.0000x reference)
//
#include <hip/hip_runtime.h>

#define N_NODES 50000
#define E_EDGES 800000
#define F_IN    128
#define EDGE_DIM 64
#define HC      256
#define NEG_SLOPE 0.2f

typedef __attribute__((ext_vector_type(8))) short short8;
typedef __attribute__((ext_vector_type(4))) float f32x4;

__device__ __forceinline__ unsigned short f2bf(float f) {
    unsigned u = __builtin_bit_cast(unsigned, f);
    u += 0x7fffu + ((u >> 16) & 1u);
    return (unsigned short)(u >> 16);
}
__device__ __forceinline__ float bf2f(unsigned short b) {
    return __builtin_bit_cast(float, (unsigned)b << 16);
}

// ---------- K_pre: zero counts/gcur, W_T bf16 [256][128], WaT bf16 [16][128], We_fold ----------
__global__ __launch_bounds__(256) void k_pre(const float* __restrict__ W,
        const float* __restrict__ att_src, const float* __restrict__ att_dst,
        const float* __restrict__ W_edge, const float* __restrict__ att_edge,
        unsigned short* __restrict__ W_T, unsigned short* __restrict__ WaT,
        float* __restrict__ We_fold, int* __restrict__ counts, int* __restrict__ gcur) {
    int idx = blockIdx.x * 256 + threadIdx.x;
    if (idx < N_NODES) counts[idx] = 0;
    if (idx == 0) *gcur = 0;
    if (idx < 32768) {
        int n = idx >> 7, k = idx & 127;
        W_T[n * 128 + k] = f2bf(W[k * 256 + n]);
    }
    if (idx < 2048) {
        int col = idx & 15, k = idx >> 4;
        const float* att = (col < 8) ? att_src : att_dst;
        int h = col & 7;
        float s = 0.f;
        #pragma unroll
        for (int c = 0; c < 32; ++c)
            s = fmaf(W[k * 256 + h * 32 + c], att[h * 32 + c], s);
        WaT[col * 128 + k] = f2bf(s);
    }
    if (idx < 512) {
        int d = idx >> 3, h = idx & 7;
        float s = 0.f;
        #pragma unroll
        for (int c = 0; c < 32; ++c)
            s = fmaf(W_edge[d * 256 + h * 32 + c], att_edge[h * 32 + c], s);
        We_fold[d * 8 + h] = s;
    }
}

// ---------- K1H: fused — blocks [0,HIST_BLOCKS) histogram, rest = MFMA node GEMM ----------
#define NT_TILES 782
#define K1_GRID 512
#define HIST_BLOCKS 782
__global__ __launch_bounds__(256, 2) void k1h(const float* __restrict__ x,
        const unsigned short* __restrict__ W_T, const unsigned short* __restrict__ WaT,
        const int4* __restrict__ dst4, int* __restrict__ counts,
        unsigned short* __restrict__ xs, float* __restrict__ a_src, float* __restrict__ a_dst) {
    __shared__ unsigned short sB[256 * 128];   // 64 KB, XOR-swizzled 16B granules
    __shared__ unsigned short sA[64 * 128];    // 16 KB
    int t = threadIdx.x;

    if (blockIdx.x < HIST_BLOCKS) {            // ---- histogram part (scheduled first)
        int i = blockIdx.x * 256 + t;
        if (i < E_EDGES / 4) {
            int4 d = dst4[i];
            atomicAdd(&counts[d.x], 1);
            atomicAdd(&counts[d.y], 1);
            atomicAdd(&counts[d.z], 1);
            atomicAdd(&counts[d.w], 1);
        }
        return;
    }
    int bid = blockIdx.x - HIST_BLOCKS;        // ---- MFMA part: 0..511

    for (int G = t; G < 4096; G += 256) {
        int n = G >> 4, gi = G & 15;
        *(int4*)&sB[(n * 16 + (gi ^ (n & 7))) * 8] = *(const int4*)&W_T[n * 128 + gi * 8];
    }
    int lane = t & 63, w = t >> 6, mr = lane & 15, g = lane >> 4;
    short8 wa[4];
    #pragma unroll
    for (int ks = 0; ks < 4; ++ks)
        wa[ks] = *(const short8*)&WaT[mr * 128 + ks * 32 + g * 8];

    bool first = true;
    for (int rt = bid; rt < NT_TILES; rt += K1_GRID) {
        if (!first) __syncthreads();
        first = false;
        for (int G = t; G < 1024; G += 256) {
            int r = G >> 4, gi = G & 15;
            int node = rt * 64 + r;
            unsigned short pk[8];
            if (node < N_NODES) {
                const float* xp = &x[(long)node * 128 + gi * 8];
                #pragma unroll
                for (int jj = 0; jj < 8; ++jj) pk[jj] = f2bf(fmaxf(xp[jj], 0.f));
            } else {
                #pragma unroll
                for (int jj = 0; jj < 8; ++jj) pk[jj] = 0;
            }
            *(int4*)&sA[(r * 16 + (gi ^ (r & 7))) * 8] = *(int4*)pk;
        }
        __syncthreads();

        f32x4 acc[17];
        #pragma unroll
        for (int i = 0; i < 17; ++i) acc[i] = (f32x4){0.f, 0.f, 0.f, 0.f};

        int r16 = w * 16 + mr;
        #pragma unroll
        for (int ks = 0; ks < 4; ++ks) {
            int pos = (ks * 4 + g) ^ (mr & 7);
            short8 a = *(const short8*)&sA[(r16 * 16 + pos) * 8];
            #pragma unroll
            for (int nt = 0; nt < 16; ++nt) {
                short8 b = *(const short8*)&sB[((nt * 16 + mr) * 16 + pos) * 8];
                acc[nt] = __builtin_amdgcn_mfma_f32_16x16x32_bf16(a, b, acc[nt], 0, 0, 0);
            }
            acc[16] = __builtin_amdgcn_mfma_f32_16x16x32_bf16(a, wa[ks], acc[16], 0, 0, 0);
        }

        #pragma unroll
        for (int r = 0; r < 4; ++r) {
            int node = rt * 64 + w * 16 + g * 4 + r;
            if (node < N_NODES) {
                #pragma unroll
                for (int nt = 0; nt < 16; ++nt)
                    xs[(long)node * 256 + nt * 16 + mr] = f2bf(acc[nt][r]);
                if (mr < 8) a_src[node * 8 + mr]       = acc[16][r];
                else        a_dst[node * 8 + (mr - 8)] = acc[16][r];
            }
        }
    }
}

// ---------- K4: allocate CSR segments (order-free) via wave scan ----------
__global__ __launch_bounds__(256) void k4_alloc(const int* __restrict__ counts,
                                                int* __restrict__ starts,
                                                int* __restrict__ cursor,
                                                int* __restrict__ gcur) {
    int n = blockIdx.x * 256 + threadIdx.x;
    int c = (n < N_NODES) ? counts[n] : 0;
    int incl = c;
    #pragma unroll
    for (int off = 1; off < 64; off <<= 1) {
        int u = __shfl_up(incl, off);
        if ((threadIdx.x & 63) >= off) incl += u;
    }
    int total = __shfl(incl, 63);
    int wavebase = 0;
    if ((threadIdx.x & 63) == 63) wavebase = atomicAdd(gcur, total);
    wavebase = __shfl(wavebase, 63);
    if (n < N_NODES) {
        int st = wavebase + incl - c;
        starts[n] = st;
        cursor[n] = st;
    }
}

// ---------- K25: multi-tile fused edge logits (b128 LDS dot) + exp + fp16 CSR scatter ----------
#define K25_TILES 8
__global__ __launch_bounds__(256) void k25_fused(const float4* __restrict__ edge_attr4,
        const float* __restrict__ We_fold,
        const int* __restrict__ src, const int* __restrict__ dst,
        const float* __restrict__ a_src, const float* __restrict__ a_dst,
        int* __restrict__ cursor,
        _Float16* __restrict__ w_perm, int* __restrict__ src_perm) {
    __shared__ __align__(16) float se[32 * 68];    // padded rows: 68 floats = 17 float4
    __shared__ __align__(16) float sfT[8 * 68];    // transposed We_fold, padded
    __shared__ int s_src[32], s_dst[32], s_pos[32];
    int t = threadIdx.x;
    for (int i = t; i < 512; i += 256)
        sfT[(i & 7) * 68 + (i >> 3)] = We_fold[i];

    int e = t >> 3, h = t & 7;
    #pragma unroll 1
    for (int it = 0; it < K25_TILES; ++it) {
        long ebase = (long)blockIdx.x * (32 * K25_TILES) + it * 32;
        __syncthreads();   // prior tile's readers done (also covers sfT on first iter)
        for (int i = t; i < 512; i += 256) {
            float4 v = edge_attr4[ebase * 16 + i];
            *(float4*)&se[(i >> 4) * 68 + (i & 15) * 4] = v;
        }
        if (t < 32) {
            int ee = ebase + t;
            int d = dst[ee];
            s_src[t] = src[ee];
            s_dst[t] = d;
            s_pos[t] = atomicAdd(&cursor[d], 1);
        }
        __syncthreads();

        const float4* sa = (const float4*)&se[e * 68];
        const float4* sb = (const float4*)&sfT[h * 68];
        float s = 0.f;
        #pragma unroll
        for (int i = 0; i < 16; ++i) {
            float4 a = sa[i], b = sb[i];
            s = fmaf(a.x, b.x, s);
            s = fmaf(a.y, b.y, s);
            s = fmaf(a.z, b.z, s);
            s = fmaf(a.w, b.w, s);
        }
        int sn = s_src[e], dn = s_dst[e];
        float v = s + a_src[sn * 8 + h] + a_dst[dn * 8 + h];
        v = (v > 0.f) ? v : NEG_SLOPE * v;
        float w = __expf(v);
        int pos = s_pos[e];
        __builtin_nontemporal_store((_Float16)w, &w_perm[(size_t)pos * 8 + h]);
        if (h == 0) __builtin_nontemporal_store(sn, &src_perm[pos]);
    }
}

// ---------- K6: wave-per-node streaming normalize + aggregation (fp16 weights, NT streams) ----------
__global__ __launch_bounds__(256) void k6_wave(
    const int* __restrict__ starts, const int* __restrict__ counts,
    const _Float16* __restrict__ w_perm, const int* __restrict__ src_perm,
    const unsigned short* __restrict__ xs, const float* __restrict__ bias,
    float* __restrict__ out) {
    int lane = threadIdx.x & 63;
    int n = blockIdx.x * 4 + (threadIdx.x >> 6);
    if (n >= N_NODES) return;
    int start = starts[n], cnt = counts[n];
    int j = lane >> 3;        // weight-slot this lane loads
    int hq = lane >> 3;       // head of this lane's 4 output cols (c = lane*4+k)

    float acc0 = 0.f, acc1 = 0.f, acc2 = 0.f, acc3 = 0.f;
    float psum = 0.f;
    for (int base = 0; base < cnt; base += 8) {
        int nk = cnt - base; if (nk > 8) nk = 8;
        float wv = (float)__builtin_nontemporal_load(&w_perm[(size_t)(start + base) * 8 + lane]);
        if (j >= nk) wv = 0.f;
        psum += wv;
        int sv = __builtin_nontemporal_load(&src_perm[start + base + (lane & 7)]);
        #pragma unroll
        for (int jj = 0; jj < 8; ++jj) {
            int s = __shfl(sv, jj);
            s = (jj < nk) ? s : 0;
            float w = __shfl(wv, jj * 8 + hq);
            ushort4 xv = *(const ushort4*)&xs[(size_t)s * 256 + lane * 4];
            acc0 = fmaf(w, bf2f(xv.x), acc0);
            acc1 = fmaf(w, bf2f(xv.y), acc1);
            acc2 = fmaf(w, bf2f(xv.z), acc2);
            acc3 = fmaf(w, bf2f(xv.w), acc3);
        }
    }
    psum += __shfl_xor(psum, 8);
    psum += __shfl_xor(psum, 16);
    psum += __shfl_xor(psum, 32);
    float denom = __shfl(psum, hq);
    float rinv = 1.0f / (denom + 1e-16f);
    float4 bv = *(const float4*)&bias[lane * 4];
    f32x4 o;
    o[0] = acc0 * rinv + bv.x;
    o[1] = acc1 * rinv + bv.y;
    o[2] = acc2 * rinv + bv.z;
    o[3] = acc3 * rinv + bv.w;
    __builtin_nontemporal_store(o, (f32x4*)&out[(size_t)n * 256 + lane * 4]);
}

extern "C" void kernel_launch(void* const* d_in, const int* in_sizes, int n_in,
                              void* d_out, int out_size, void* d_ws, size_t ws_size,
                              hipStream_t stream) {
    const float* x         = (const float*)d_in[0];
    const int*   ei        = (const int*)d_in[1];   // [2,E]: src = ei, dst = ei+E
    const float* edge_attr = (const float*)d_in[2];
    const float* W         = (const float*)d_in[3];
    const float* att_src   = (const float*)d_in[4];
    const float* att_dst   = (const float*)d_in[5];
    const float* W_edge    = (const float*)d_in[6];
    const float* att_edge  = (const float*)d_in[7];
    const float* bias      = (const float*)d_in[8];
    float* out = (float*)d_out;

    const int* e_src = ei;
    const int* e_dst = ei + E_EDGES;

    char* p = (char*)d_ws;
    unsigned short* xs = (unsigned short*)p; p += (size_t)N_NODES * HC * 2;    // 25.6 MB
    float* a_src   = (float*)p; p += (size_t)N_NODES * 8 * 4;                  // 1.6 MB
    float* a_dst   = (float*)p; p += (size_t)N_NODES * 8 * 4;                  // 1.6 MB
    _Float16* w_perm = (_Float16*)p; p += (size_t)E_EDGES * 8 * 2 + 256;       // 12.8 MB (+pad)
    int* src_perm  = (int*)p;   p += (size_t)E_EDGES * 4 + 256;                // 3.2 MB (+pad)
    unsigned short* W_T  = (unsigned short*)p; p += 32768 * 2;                 // 64 KB
    unsigned short* WaT  = (unsigned short*)p; p += 2048 * 2;                  // 4 KB
    float* We_fold = (float*)p; p += 512 * 4;                                  // 2 KB
    int* counts    = (int*)p;   p += 200192;
    int* starts    = (int*)p;   p += 200192;
    int* cursor    = (int*)p;   p += 200192;
    int* gcur      = (int*)p;   p += 256;

    hipLaunchKernelGGL(k_pre, dim3(196), dim3(256), 0, stream,
                       W, att_src, att_dst, W_edge, att_edge, W_T, WaT, We_fold, counts, gcur);
    hipLaunchKernelGGL(k1h, dim3(HIST_BLOCKS + K1_GRID), dim3(256), 0, stream,
                       x, W_T, WaT, (const int4*)e_dst, counts, xs, a_src, a_dst);
    hipLaunchKernelGGL(k4_alloc, dim3(196), dim3(256), 0, stream,
                       counts, starts, cursor, gcur);
    hipLaunchKernelGGL(k25_fused, dim3(E_EDGES / (32 * K25_TILES)), dim3(256), 0, stream,
                       (const float4*)edge_attr, We_fold, e_src, e_dst,
                       a_src, a_dst, cursor, w_perm, src_perm);
    hipLaunchKernelGGL(k6_wave, dim3(N_NODES / 4), dim3(256), 0, stream,
                       starts, counts, w_perm, src_perm, xs, bias, out);
}

// Round 12
// 208.523 us; speedup vs baseline: 1.0682x; 1.0682x over previous
//
#include <hip/hip_runtime.h>

#define N_NODES 50000
#define E_EDGES 800000
#define F_IN    128
#define EDGE_DIM 64
#define HC      256
#define NEG_SLOPE 0.2f

typedef __attribute__((ext_vector_type(8))) short short8;
typedef __attribute__((ext_vector_type(4))) float f32x4;

__device__ __forceinline__ unsigned short f2bf(float f) {
    unsigned u = __builtin_bit_cast(unsigned, f);
    u += 0x7fffu + ((u >> 16) & 1u);
    return (unsigned short)(u >> 16);
}
__device__ __forceinline__ float bf2f(unsigned short b) {
    return __builtin_bit_cast(float, (unsigned)b << 16);
}

// ---------- K_pre: zero counts/gcur, W_T bf16 [256][128], WaT bf16 [16][128], We_fold ----------
__global__ __launch_bounds__(256) void k_pre(const float* __restrict__ W,
        const float* __restrict__ att_src, const float* __restrict__ att_dst,
        const float* __restrict__ W_edge, const float* __restrict__ att_edge,
        unsigned short* __restrict__ W_T, unsigned short* __restrict__ WaT,
        float* __restrict__ We_fold, int* __restrict__ counts, int* __restrict__ gcur) {
    int idx = blockIdx.x * 256 + threadIdx.x;
    if (idx < N_NODES) counts[idx] = 0;
    if (idx == 0) *gcur = 0;
    if (idx < 32768) {
        int n = idx >> 7, k = idx & 127;
        W_T[n * 128 + k] = f2bf(W[k * 256 + n]);
    }
    if (idx < 2048) {
        int col = idx & 15, k = idx >> 4;
        const float* att = (col < 8) ? att_src : att_dst;
        int h = col & 7;
        float s = 0.f;
        #pragma unroll
        for (int c = 0; c < 32; ++c)
            s = fmaf(W[k * 256 + h * 32 + c], att[h * 32 + c], s);
        WaT[col * 128 + k] = f2bf(s);
    }
    if (idx < 512) {
        int d = idx >> 3, h = idx & 7;
        float s = 0.f;
        #pragma unroll
        for (int c = 0; c < 32; ++c)
            s = fmaf(W_edge[d * 256 + h * 32 + c], att_edge[h * 32 + c], s);
        We_fold[d * 8 + h] = s;
    }
}

// ---------- K1H: fused — hist blocks compute counts AND slot[e]; rest = MFMA node GEMM ----------
#define NT_TILES 782
#define K1_GRID 512
#define HIST_BLOCKS 782
__global__ __launch_bounds__(256, 2) void k1h(const float* __restrict__ x,
        const unsigned short* __restrict__ W_T, const unsigned short* __restrict__ WaT,
        const int4* __restrict__ dst4, int* __restrict__ counts, int4* __restrict__ slot4,
        unsigned short* __restrict__ xs, float* __restrict__ a_src, float* __restrict__ a_dst) {
    __shared__ unsigned short sB[256 * 128];   // 64 KB, XOR-swizzled 16B granules
    __shared__ unsigned short sA[64 * 128];    // 16 KB
    int t = threadIdx.x;

    if (blockIdx.x < HIST_BLOCKS) {            // ---- histogram + slot assignment
        int i = blockIdx.x * 256 + t;
        if (i < E_EDGES / 4) {
            int4 d = dst4[i];
            int4 sl;
            sl.x = atomicAdd(&counts[d.x], 1);
            sl.y = atomicAdd(&counts[d.y], 1);
            sl.z = atomicAdd(&counts[d.z], 1);
            sl.w = atomicAdd(&counts[d.w], 1);
            slot4[i] = sl;
        }
        return;
    }
    int bid = blockIdx.x - HIST_BLOCKS;        // ---- MFMA part: 0..511

    for (int G = t; G < 4096; G += 256) {
        int n = G >> 4, gi = G & 15;
        *(int4*)&sB[(n * 16 + (gi ^ (n & 7))) * 8] = *(const int4*)&W_T[n * 128 + gi * 8];
    }
    int lane = t & 63, w = t >> 6, mr = lane & 15, g = lane >> 4;
    short8 wa[4];
    #pragma unroll
    for (int ks = 0; ks < 4; ++ks)
        wa[ks] = *(const short8*)&WaT[mr * 128 + ks * 32 + g * 8];

    bool first = true;
    for (int rt = bid; rt < NT_TILES; rt += K1_GRID) {
        if (!first) __syncthreads();
        first = false;
        for (int G = t; G < 1024; G += 256) {
            int r = G >> 4, gi = G & 15;
            int node = rt * 64 + r;
            unsigned short pk[8];
            if (node < N_NODES) {
                const float* xp = &x[(long)node * 128 + gi * 8];
                #pragma unroll
                for (int jj = 0; jj < 8; ++jj) pk[jj] = f2bf(fmaxf(xp[jj], 0.f));
            } else {
                #pragma unroll
                for (int jj = 0; jj < 8; ++jj) pk[jj] = 0;
            }
            *(int4*)&sA[(r * 16 + (gi ^ (r & 7))) * 8] = *(int4*)pk;
        }
        __syncthreads();

        f32x4 acc[17];
        #pragma unroll
        for (int i = 0; i < 17; ++i) acc[i] = (f32x4){0.f, 0.f, 0.f, 0.f};

        int r16 = w * 16 + mr;
        #pragma unroll
        for (int ks = 0; ks < 4; ++ks) {
            int pos = (ks * 4 + g) ^ (mr & 7);
            short8 a = *(const short8*)&sA[(r16 * 16 + pos) * 8];
            #pragma unroll
            for (int nt = 0; nt < 16; ++nt) {
                short8 b = *(const short8*)&sB[((nt * 16 + mr) * 16 + pos) * 8];
                acc[nt] = __builtin_amdgcn_mfma_f32_16x16x32_bf16(a, b, acc[nt], 0, 0, 0);
            }
            acc[16] = __builtin_amdgcn_mfma_f32_16x16x32_bf16(a, wa[ks], acc[16], 0, 0, 0);
        }

        #pragma unroll
        for (int r = 0; r < 4; ++r) {
            int node = rt * 64 + w * 16 + g * 4 + r;
            if (node < N_NODES) {
                #pragma unroll
                for (int nt = 0; nt < 16; ++nt)
                    xs[(long)node * 256 + nt * 16 + mr] = f2bf(acc[nt][r]);
                if (mr < 8) a_src[node * 8 + mr]       = acc[16][r];
                else        a_dst[node * 8 + (mr - 8)] = acc[16][r];
            }
        }
    }
}

// ---------- K4: exclusive-scan counts -> starts via wave scan + global atomic base ----------
__global__ __launch_bounds__(256) void k4_alloc(const int* __restrict__ counts,
                                                int* __restrict__ starts,
                                                int* __restrict__ gcur) {
    int n = blockIdx.x * 256 + threadIdx.x;
    int c = (n < N_NODES) ? counts[n] : 0;
    int incl = c;
    #pragma unroll
    for (int off = 1; off < 64; off <<= 1) {
        int u = __shfl_up(incl, off);
        if ((threadIdx.x & 63) >= off) incl += u;
    }
    int total = __shfl(incl, 63);
    int wavebase = 0;
    if ((threadIdx.x & 63) == 63) wavebase = atomicAdd(gcur, total);
    wavebase = __shfl(wavebase, 63);
    if (n < N_NODES) starts[n] = wavebase + incl - c;
}

// ---------- K25: fused edge logits (b128 LDS dot) + exp + scatter, NO atomics ----------
__global__ __launch_bounds__(256) void k25_fused(const float4* __restrict__ edge_attr4,
        const float* __restrict__ We_fold,
        const int* __restrict__ src, const int* __restrict__ dst,
        const int* __restrict__ slot, const int* __restrict__ starts,
        const float* __restrict__ a_src, const float* __restrict__ a_dst,
        _Float16* __restrict__ w_perm, int* __restrict__ src_perm) {
    __shared__ __align__(16) float se[32 * 68];    // padded rows: 68 floats = 17 float4
    __shared__ __align__(16) float sfT[8 * 68];    // transposed We_fold, padded
    __shared__ int s_src[32], s_dstn[32], s_pos[32];
    int t = threadIdx.x;
    long ebase = (long)blockIdx.x * 32;
    for (int i = t; i < 512; i += 256)
        sfT[(i & 7) * 68 + (i >> 3)] = We_fold[i];
    for (int i = t; i < 512; i += 256) {
        float4 v = edge_attr4[ebase * 16 + i];
        *(float4*)&se[(i >> 4) * 68 + (i & 15) * 4] = v;
    }
    if (t < 32) {
        int ee = ebase + t;
        int dn = dst[ee];
        s_dstn[t] = dn;
        s_src[t] = src[ee];
        s_pos[t] = starts[dn] + slot[ee];   // no atomic — precomputed slot
    }
    __syncthreads();
    int e = t >> 3, h = t & 7;
    const float4* sa = (const float4*)&se[e * 68];
    const float4* sb = (const float4*)&sfT[h * 68];
    float s = 0.f;
    #pragma unroll
    for (int i = 0; i < 16; ++i) {
        float4 a = sa[i], b = sb[i];
        s = fmaf(a.x, b.x, s);
        s = fmaf(a.y, b.y, s);
        s = fmaf(a.z, b.z, s);
        s = fmaf(a.w, b.w, s);
    }
    int sn = s_src[e], dn = s_dstn[e];
    float v = s + a_src[sn * 8 + h] + a_dst[dn * 8 + h];
    v = (v > 0.f) ? v : NEG_SLOPE * v;
    float w = __expf(v);
    int pos = s_pos[e];
    w_perm[(size_t)pos * 8 + h] = (_Float16)w;     // normal store: keep in L2/L3 for k6
    if (h == 0) src_perm[pos] = sn;
}

// ---------- K6: wave-per-node streaming normalize + aggregation (fp16 weights) ----------
__global__ __launch_bounds__(256) void k6_wave(
    const int* __restrict__ starts, const int* __restrict__ counts,
    const _Float16* __restrict__ w_perm, const int* __restrict__ src_perm,
    const unsigned short* __restrict__ xs, const float* __restrict__ bias,
    float* __restrict__ out) {
    int lane = threadIdx.x & 63;
    int n = blockIdx.x * 4 + (threadIdx.x >> 6);
    if (n >= N_NODES) return;
    int start = starts[n], cnt = counts[n];
    int j = lane >> 3;        // weight-slot this lane loads
    int hq = lane >> 3;       // head of this lane's 4 output cols (c = lane*4+k)

    float acc0 = 0.f, acc1 = 0.f, acc2 = 0.f, acc3 = 0.f;
    float psum = 0.f;
    for (int base = 0; base < cnt; base += 8) {
        int nk = cnt - base; if (nk > 8) nk = 8;
        float wv = (float)w_perm[(size_t)(start + base) * 8 + lane];   // 128B coalesced
        if (j >= nk) wv = 0.f;
        psum += wv;
        int sv = src_perm[start + base + (lane & 7)];
        #pragma unroll
        for (int jj = 0; jj < 8; ++jj) {
            int s = __shfl(sv, jj);
            s = (jj < nk) ? s : 0;
            float w = __shfl(wv, jj * 8 + hq);
            ushort4 xv = *(const ushort4*)&xs[(size_t)s * 256 + lane * 4];
            acc0 = fmaf(w, bf2f(xv.x), acc0);
            acc1 = fmaf(w, bf2f(xv.y), acc1);
            acc2 = fmaf(w, bf2f(xv.z), acc2);
            acc3 = fmaf(w, bf2f(xv.w), acc3);
        }
    }
    psum += __shfl_xor(psum, 8);
    psum += __shfl_xor(psum, 16);
    psum += __shfl_xor(psum, 32);
    float denom = __shfl(psum, hq);
    float rinv = 1.0f / (denom + 1e-16f);
    float4 bv = *(const float4*)&bias[lane * 4];
    f32x4 o;
    o[0] = acc0 * rinv + bv.x;
    o[1] = acc1 * rinv + bv.y;
    o[2] = acc2 * rinv + bv.z;
    o[3] = acc3 * rinv + bv.w;
    __builtin_nontemporal_store(o, (f32x4*)&out[(size_t)n * 256 + lane * 4]);
}

extern "C" void kernel_launch(void* const* d_in, const int* in_sizes, int n_in,
                              void* d_out, int out_size, void* d_ws, size_t ws_size,
                              hipStream_t stream) {
    const float* x         = (const float*)d_in[0];
    const int*   ei        = (const int*)d_in[1];   // [2,E]: src = ei, dst = ei+E
    const float* edge_attr = (const float*)d_in[2];
    const float* W         = (const float*)d_in[3];
    const float* att_src   = (const float*)d_in[4];
    const float* att_dst   = (const float*)d_in[5];
    const float* W_edge    = (const float*)d_in[6];
    const float* att_edge  = (const float*)d_in[7];
    const float* bias      = (const float*)d_in[8];
    float* out = (float*)d_out;

    const int* e_src = ei;
    const int* e_dst = ei + E_EDGES;

    char* p = (char*)d_ws;
    unsigned short* xs = (unsigned short*)p; p += (size_t)N_NODES * HC * 2;    // 25.6 MB
    float* a_src   = (float*)p; p += (size_t)N_NODES * 8 * 4;                  // 1.6 MB
    float* a_dst   = (float*)p; p += (size_t)N_NODES * 8 * 4;                  // 1.6 MB
    _Float16* w_perm = (_Float16*)p; p += (size_t)E_EDGES * 8 * 2 + 256;       // 12.8 MB (+pad)
    int* src_perm  = (int*)p;   p += (size_t)E_EDGES * 4 + 256;                // 3.2 MB (+pad)
    int* slot      = (int*)p;   p += (size_t)E_EDGES * 4 + 256;                // 3.2 MB (+pad)
    unsigned short* W_T  = (unsigned short*)p; p += 32768 * 2;                 // 64 KB
    unsigned short* WaT  = (unsigned short*)p; p += 2048 * 2;                  // 4 KB
    float* We_fold = (float*)p; p += 512 * 4;                                  // 2 KB
    int* counts    = (int*)p;   p += 200192;
    int* starts    = (int*)p;   p += 200192;
    int* gcur      = (int*)p;   p += 256;

    hipLaunchKernelGGL(k_pre, dim3(196), dim3(256), 0, stream,
                       W, att_src, att_dst, W_edge, att_edge, W_T, WaT, We_fold, counts, gcur);
    hipLaunchKernelGGL(k1h, dim3(HIST_BLOCKS + K1_GRID), dim3(256), 0, stream,
                       x, W_T, WaT, (const int4*)e_dst, counts, (int4*)slot, xs, a_src, a_dst);
    hipLaunchKernelGGL(k4_alloc, dim3(196), dim3(256), 0, stream,
                       counts, starts, gcur);
    hipLaunchKernelGGL(k25_fused, dim3(E_EDGES / 32), dim3(256), 0, stream,
                       (const float4*)edge_attr, We_fold, e_src, e_dst, slot, starts,
                       a_src, a_dst, w_perm, src_perm);
    hipLaunchKernelGGL(k6_wave, dim3(N_NODES / 4), dim3(256), 0, stream,
                       starts, counts, w_perm, src_perm, xs, bias, out);
}